// Round 6
// baseline (118.210 us; speedup 1.0000x reference)
//
#include <hip/hip_runtime.h>

// ECE/MCE: softmax-confidence calibration histogram.
// logits f32 [N=131072, C=1000], labels int32 [N] -> out f32 [2] = (ece, mce).
//
// Per row: conf = 1/sum(exp(x - max)), pred = argmax(x) (first occurrence),
// bin = clip(ceil(conf*10)-1, 0, 9); accumulate (cnt, conf_sum, acc_sum).
//
// R6: LDS-staged streaming. Each block owns 64 consecutive rows (256,000 B)
// and streams them via global_load_lds (16B/lane, 1024B-aligned contiguous
// wave requests -- the same access shape as the 6.6 TB/s fill kernels),
// double-buffered 4-row groups; one wave reduces one row from LDS while the
// next group's loads are in flight (2-phase pattern, barrier drains vmcnt).

constexpr int N_BINS = 10;
constexpr int NCOLS  = 1000;
constexpr int NV4    = NCOLS / 4;        // 250 float4 per row
constexpr int BLOCK  = 256;              // 4 waves
constexpr int GRID   = 2048;             // 64 rows/block exactly at N=131072
constexpr int GROUP  = 4;                // rows staged per iteration (1/wave)
constexpr int GROUP_F4 = GROUP * NV4;    // 1000 float4 per group

using f4 = __attribute__((ext_vector_type(4))) float;

__device__ __forceinline__ void stage_group(const float* __restrict__ gsrc,
                                            float* __restrict__ lbuf,
                                            int tid, int valid_f4)
{
    // flat float4 index = r*BLOCK + tid; wave-uniform LDS base = chunk start.
    #pragma unroll
    for (int r = 0; r < (GROUP_F4 + BLOCK - 1) / BLOCK; ++r) {
        int flat = r * BLOCK + tid;
        if (flat < valid_f4) {
            const float* g = gsrc + (size_t)flat * 4;
            float*       l = lbuf + (size_t)(flat & ~63) * 4;  // uniform per wave
            __builtin_amdgcn_global_load_lds(
                (const __attribute__((address_space(1))) unsigned int*)g,
                (__attribute__((address_space(3))) unsigned int*)l,
                16, 0, 0);
        }
    }
}

__global__ __launch_bounds__(BLOCK) void ece_rows_kernel(
    const float* __restrict__ logits,
    const int*   __restrict__ labels,
    float*       __restrict__ g_acc,   // [3*N_BINS]: cnt | conf_sum | acc_sum
    int nrows)
{
    __shared__ float s_buf[2][GROUP * NCOLS];   // 2 x 16000 B
    __shared__ float s_bins[BLOCK / 64][3][N_BINS];

    const int tid  = threadIdx.x;
    const int wave = tid >> 6;
    const int lane = tid & 63;

    for (int i = tid; i < (BLOCK / 64) * 3 * N_BINS; i += BLOCK)
        (&s_bins[0][0][0])[i] = 0.0f;

    const int rpb     = (nrows + GRID - 1) / GRID;        // 64
    const int rbeg    = blockIdx.x * rpb;
    const int ngroups = (rpb + GROUP - 1) / GROUP;        // 16

    // prologue: stage group 0
    {
        int grow = rbeg;
        int vf4  = min(GROUP_F4, max(0, (nrows - grow)) * NV4);
        if (vf4 > 0) stage_group(logits + (size_t)grow * NCOLS, s_buf[0], tid, vf4);
    }
    __syncthreads();                       // drains vmcnt(0): group 0 resident

    for (int g = 0; g < ngroups; ++g) {
        // issue next group's loads first (latency hides under compute)
        if (g + 1 < ngroups) {
            int grow = rbeg + (g + 1) * GROUP;
            int vf4  = min(GROUP_F4, max(0, (nrows - grow)) * NV4);
            if (vf4 > 0)
                stage_group(logits + (size_t)grow * NCOLS, s_buf[(g + 1) & 1], tid, vf4);
        }

        const int row = rbeg + g * GROUP + wave;
        if (row < nrows) {
            const int lab = labels[row];
            const f4* rp = reinterpret_cast<const f4*>(&s_buf[g & 1][(size_t)wave * NCOLS]);

            f4 a0 = rp[lane];
            f4 a1 = rp[lane + 64];
            f4 a2 = rp[lane + 128];
            f4 a3;
            if (lane + 192 < NV4) a3 = rp[lane + 192];          // lanes 0..57
            else                  a3 = (f4){-INFINITY, -INFINITY, -INFINITY, -INFINITY};

            // ---- per-lane max + first-occurrence argmax over 16 values ----
            float maxv = -INFINITY;
            int   maxi = 0x7fffffff;
            {
                int base = 4 * lane;
                #define UPD(val, idx) if ((val) > maxv) { maxv = (val); maxi = (idx); }
                UPD(a0.x, base)       UPD(a0.y, base + 1)   UPD(a0.z, base + 2)   UPD(a0.w, base + 3)
                base = 4 * (lane + 64);
                UPD(a1.x, base)       UPD(a1.y, base + 1)   UPD(a1.z, base + 2)   UPD(a1.w, base + 3)
                base = 4 * (lane + 128);
                UPD(a2.x, base)       UPD(a2.y, base + 1)   UPD(a2.z, base + 2)   UPD(a2.w, base + 3)
                base = 4 * (lane + 192);
                UPD(a3.x, base)       UPD(a3.y, base + 1)   UPD(a3.z, base + 2)   UPD(a3.w, base + 3)
                #undef UPD
            }

            // wave-wide (max, argmax) butterfly; ties -> smaller index
            #pragma unroll
            for (int off = 32; off > 0; off >>= 1) {
                float ov = __shfl_xor(maxv, off);
                int   oi = __shfl_xor(maxi, off);
                if (ov > maxv || (ov == maxv && oi < maxi)) { maxv = ov; maxi = oi; }
            }

            // ---- sum of exp(x - max); -INF pads give exp(-inf)=0 ----
            float s = __expf(a0.x - maxv) + __expf(a0.y - maxv)
                    + __expf(a0.z - maxv) + __expf(a0.w - maxv)
                    + __expf(a1.x - maxv) + __expf(a1.y - maxv)
                    + __expf(a1.z - maxv) + __expf(a1.w - maxv)
                    + __expf(a2.x - maxv) + __expf(a2.y - maxv)
                    + __expf(a2.z - maxv) + __expf(a2.w - maxv)
                    + __expf(a3.x - maxv) + __expf(a3.y - maxv)
                    + __expf(a3.z - maxv) + __expf(a3.w - maxv);
            #pragma unroll
            for (int off = 32; off > 0; off >>= 1)
                s += __shfl_xor(s, off);

            if (lane == 0) {
                float conf = 1.0f / s;                 // exp(0)/sum == max softmax
                float acc  = (maxi == lab) ? 1.0f : 0.0f;
                int b = (int)ceilf(conf * (float)N_BINS) - 1;
                b = min(max(b, 0), N_BINS - 1);
                s_bins[wave][0][b] += 1.0f;            // lane-0-private slots
                s_bins[wave][1][b] += conf;
                s_bins[wave][2][b] += acc;
            }
        }

        // barrier: (a) all waves done reading buf[g&1] before re-stage,
        // (b) compiler drains vmcnt(0) -> next group resident.
        __syncthreads();
    }

    // combine this block's waves, one atomic per (component, bin) per block
    if (tid < 3 * N_BINS) {
        int c = tid / N_BINS;
        int b = tid % N_BINS;
        float t = 0.0f;
        #pragma unroll
        for (int w = 0; w < BLOCK / 64; ++w) t += s_bins[w][c][b];
        if (t != 0.0f) atomicAdd(&g_acc[c * N_BINS + b], t);
    }
}

__global__ void ece_final_kernel(const float* __restrict__ g_acc,
                                 float* __restrict__ out, float inv_n)
{
    if (threadIdx.x == 0) {
        float ece = 0.0f, mce = 0.0f;
        for (int b = 0; b < N_BINS; ++b) {
            float cnt = g_acc[b];
            float cs  = g_acc[N_BINS + b];
            float as  = g_acc[2 * N_BINS + b];
            if (cnt > 0.0f) {
                float gap = fabsf((cs - as) / cnt);
                ece += gap * cnt * inv_n;
                mce  = fmaxf(mce, gap);
            }
        }
        out[0] = ece;
        out[1] = mce;
    }
}

extern "C" void kernel_launch(void* const* d_in, const int* in_sizes, int n_in,
                              void* d_out, int out_size, void* d_ws, size_t ws_size,
                              hipStream_t stream)
{
    const float* logits = (const float*)d_in[0];
    const int*   labels = (const int*)d_in[1];
    const int    nrows  = in_sizes[1];

    float* g_acc = (float*)d_ws;
    hipMemsetAsync(d_ws, 0, 3 * N_BINS * sizeof(float), stream);

    ece_rows_kernel<<<GRID, BLOCK, 0, stream>>>(logits, labels, g_acc, nrows);
    ece_final_kernel<<<1, 64, 0, stream>>>(g_acc, (float*)d_out, 1.0f / (float)nrows);
}

// Round 7
// 110.909 us; speedup vs baseline: 1.0658x; 1.0658x over previous
//
#include <hip/hip_runtime.h>

// ECE/MCE: softmax-confidence calibration histogram.
// logits f32 [N=131072, C=1000], labels int32 [N] -> out f32 [2] = (ece, mce).
//
// Per row: conf = 1/sum(exp(x - max)), pred = argmax(x) (first occurrence),
// bin = clip(ceil(conf*10)-1, 0, 9); accumulate (cnt, conf_sum, acc_sum).
//
// R7 = R5 (two-pass register-resident row, 1-row prefetch, block-adjacent
// interleave: block owns 64 consecutive rows, waves take rbeg+w+4i) with
// NON-TEMPORAL REMOVED: rows are 4000B (16B-aligned only), so each 1024B
// wave-request straddles a 17th cache line; with normal caching the adjacent
// row's request hits that line in L2, with nt it was a +6% HBM overfetch.
// (R6's LDS-staged variant regressed 103->118: barrier-drain per group.)

constexpr int N_BINS = 10;
constexpr int NCOLS  = 1000;
constexpr int NV4    = NCOLS / 4;   // 250 float4 per row
constexpr int BLOCK  = 256;         // 4 waves/block
constexpr int GRID   = 2048;        // 64 rows per block exactly

using f4 = __attribute__((ext_vector_type(4))) float;

__device__ __forceinline__ void load_row(const float* __restrict__ logits,
                                         int row, int lane,
                                         f4& x0, f4& x1, f4& x2, f4& x3)
{
    const f4* rp = reinterpret_cast<const f4*>(logits + (size_t)row * NCOLS);
    x0 = rp[lane];
    x1 = rp[lane + 64];
    x2 = rp[lane + 128];
    if (lane + 192 < NV4) {                  // lanes 0..57; exec-masked, no OOB
        x3 = rp[lane + 192];
    } else {
        x3 = (f4){-INFINITY, -INFINITY, -INFINITY, -INFINITY};
    }
}

__global__ __launch_bounds__(BLOCK) void ece_rows_kernel(
    const float* __restrict__ logits,
    const int*   __restrict__ labels,
    float*       __restrict__ g_acc,   // [3*N_BINS]: cnt | conf_sum | acc_sum
    int nrows)
{
    __shared__ float s_bins[BLOCK / 64][3][N_BINS];

    const int wave = threadIdx.x >> 6;
    const int lane = threadIdx.x & 63;

    for (int i = threadIdx.x; i < (BLOCK / 64) * 3 * N_BINS; i += BLOCK)
        (&s_bins[0][0][0])[i] = 0.0f;
    __syncthreads();

    // block owns a contiguous run of rows; waves interleave stride-4 within it
    const int rpb  = (nrows + GRID - 1) / GRID;         // rows per block (=64)
    const int rbeg = blockIdx.x * rpb;
    const int rend = min(rbeg + rpb, nrows);

    f4 a0, a1, a2, a3;
    int row = rbeg + wave;
    if (row < rend) load_row(logits, row, lane, a0, a1, a2, a3);

    while (row < rend) {
        const int nxt = row + (BLOCK / 64);  // wave-uniform, stride 4
        const int lab = labels[row];         // issued early

        // prefetch next row (hidden under this row's processing)
        f4 b0, b1, b2, b3;
        if (nxt < rend) load_row(logits, nxt, lane, b0, b1, b2, b3);

        // ---- per-lane max + first-occurrence argmax over 16 values ----
        float maxv = -INFINITY;
        int   maxi = 0x7fffffff;
        {
            int base = 4 * lane;
            #define UPD(val, idx) if ((val) > maxv) { maxv = (val); maxi = (idx); }
            UPD(a0.x, base)       UPD(a0.y, base + 1)   UPD(a0.z, base + 2)   UPD(a0.w, base + 3)
            base = 4 * (lane + 64);
            UPD(a1.x, base)       UPD(a1.y, base + 1)   UPD(a1.z, base + 2)   UPD(a1.w, base + 3)
            base = 4 * (lane + 128);
            UPD(a2.x, base)       UPD(a2.y, base + 1)   UPD(a2.z, base + 2)   UPD(a2.w, base + 3)
            base = 4 * (lane + 192);
            UPD(a3.x, base)       UPD(a3.y, base + 1)   UPD(a3.z, base + 2)   UPD(a3.w, base + 3)
            #undef UPD
        }

        // wave-wide (max, argmax) butterfly; ties -> smaller index
        #pragma unroll
        for (int off = 32; off > 0; off >>= 1) {
            float ov = __shfl_xor(maxv, off);
            int   oi = __shfl_xor(maxi, off);
            if (ov > maxv || (ov == maxv && oi < maxi)) { maxv = ov; maxi = oi; }
        }

        // ---- sum of exp(x - max); -INF pads give exp(-inf)=0 ----
        float s = __expf(a0.x - maxv) + __expf(a0.y - maxv)
                + __expf(a0.z - maxv) + __expf(a0.w - maxv)
                + __expf(a1.x - maxv) + __expf(a1.y - maxv)
                + __expf(a1.z - maxv) + __expf(a1.w - maxv)
                + __expf(a2.x - maxv) + __expf(a2.y - maxv)
                + __expf(a2.z - maxv) + __expf(a2.w - maxv)
                + __expf(a3.x - maxv) + __expf(a3.y - maxv)
                + __expf(a3.z - maxv) + __expf(a3.w - maxv);
        #pragma unroll
        for (int off = 32; off > 0; off >>= 1)
            s += __shfl_xor(s, off);

        if (lane == 0) {
            float conf = 1.0f / s;                   // exp(0)/sum == max softmax
            float acc  = (maxi == lab) ? 1.0f : 0.0f;
            int b = (int)ceilf(conf * (float)N_BINS) - 1;
            b = min(max(b, 0), N_BINS - 1);
            s_bins[wave][0][b] += 1.0f;              // lane-0-private slots
            s_bins[wave][1][b] += conf;
            s_bins[wave][2][b] += acc;
        }

        a0 = b0; a1 = b1; a2 = b2; a3 = b3;
        row = nxt;
    }

    __syncthreads();
    // combine this block's waves, one atomic per (component, bin) per block
    if (threadIdx.x < 3 * N_BINS) {
        int c = threadIdx.x / N_BINS;
        int b = threadIdx.x % N_BINS;
        float t = 0.0f;
        #pragma unroll
        for (int w = 0; w < BLOCK / 64; ++w) t += s_bins[w][c][b];
        if (t != 0.0f) atomicAdd(&g_acc[c * N_BINS + b], t);
    }
}

__global__ void ece_final_kernel(const float* __restrict__ g_acc,
                                 float* __restrict__ out, float inv_n)
{
    if (threadIdx.x == 0) {
        float ece = 0.0f, mce = 0.0f;
        for (int b = 0; b < N_BINS; ++b) {
            float cnt = g_acc[b];
            float cs  = g_acc[N_BINS + b];
            float as  = g_acc[2 * N_BINS + b];
            if (cnt > 0.0f) {
                float gap = fabsf((cs - as) / cnt);
                ece += gap * cnt * inv_n;
                mce  = fmaxf(mce, gap);
            }
        }
        out[0] = ece;
        out[1] = mce;
    }
}

extern "C" void kernel_launch(void* const* d_in, const int* in_sizes, int n_in,
                              void* d_out, int out_size, void* d_ws, size_t ws_size,
                              hipStream_t stream)
{
    const float* logits = (const float*)d_in[0];
    const int*   labels = (const int*)d_in[1];
    const int    nrows  = in_sizes[1];

    float* g_acc = (float*)d_ws;
    hipMemsetAsync(d_ws, 0, 3 * N_BINS * sizeof(float), stream);

    ece_rows_kernel<<<GRID, BLOCK, 0, stream>>>(logits, labels, g_acc, nrows);
    ece_final_kernel<<<1, 64, 0, stream>>>(g_acc, (float*)d_out, 1.0f / (float)nrows);
}